// Round 1
// baseline (94.583 us; speedup 1.0000x reference)
//
#include <hip/hip_runtime.h>
#include <hip/hip_bf16.h>

// Problem constants
//   x:   [4096, 4096] f32
//   w:   [4096, 7, 64] f32   (weight[j*64+k][a][n])
//   w1:  [64, 4096] f32      (lowrank_first)
//   w2:  [4096, 64] f32      (lowrank_second)
//   fwd: [64, 7] i32         (forward_indices; idx = j*7 + a)
//   out: [4096, 4096] f32
//
// out block p = sum_s x[:, j_s*64:+64] @ w[j_s,:,a_s,:]  +  T @ W2_p^T
// with T = x @ w1^T.  Per p: GEMM [4096,512] x [512,64], K = 7*64 + 64.

#define DEVINL __device__ __forceinline__

typedef __attribute__((ext_vector_type(8))) short bfx8;   // 8 bf16 (4 VGPRs)
typedef __attribute__((ext_vector_type(4))) float fx4;

DEVINL short f2bf(float f) {   // round-to-nearest-even f32 -> bf16 bits
  unsigned u = __builtin_bit_cast(unsigned, f);
  unsigned r = 0x7FFFu + ((u >> 16) & 1u);
  return (short)((u + r) >> 16);
}

// XOR swizzle: tiles are [rows][64 cols] bf16, row stride 128 B.
// byte offset = row*128 + (colbyte ^ ((row&7)<<4))  -> ds_read_b128 conflict-free.
DEVINL int swzb(int row, int kbyte) { return (row << 7) + (kbyte ^ ((row & 7) << 4)); }

DEVINL void gload16(const void* g, void* l) {
  __builtin_amdgcn_global_load_lds(
      (const __attribute__((address_space(1))) unsigned int*)g,
      (__attribute__((address_space(3))) unsigned int*)l, 16, 0, 0);
}

// ---------------------------------------------------------------------------
// P0: build Bmat [64 p][8 t][64 n][64 k] bf16 pre-swizzled, and W1b
//     [64 jc][64 r][64 k] bf16 pre-swizzled (w1b[jc] holds w1[:, jc*64:+64]).
// ---------------------------------------------------------------------------
__global__ void prep_b_kern(const float* __restrict__ weight, const float* __restrict__ w1,
                            const float* __restrict__ w2, const int* __restrict__ fwd,
                            unsigned short* __restrict__ bmat, unsigned short* __restrict__ w1b) {
  int cid = blockIdx.x, tid = threadIdx.x;
  if (cid < 512) {
    int p = cid >> 3, t = cid & 7;
    unsigned short* dst = bmat + (size_t)cid * 4096;
    if (t < 7) {
      int idx = fwd[p * 7 + t];
      int j = idx / 7, a = idx - j * 7;
      int k = tid >> 2, n0 = (tid & 3) << 4;
      const float* src = weight + ((size_t)(j * 64 + k) * 7 + a) * 64 + n0;
#pragma unroll
      for (int e = 0; e < 16; ++e) {
        int n = n0 + e;
        dst[(n << 6) + ((((k << 1) ^ ((n & 7) << 4))) >> 1)] = f2bf(src[e]);
      }
    } else {
      // lowrank rows: B[448+r][n] = w2[p*64+n][r]
      int n = tid >> 2, r0 = (tid & 3) << 4;
      const float* src = w2 + ((size_t)(p * 64 + n)) * 64 + r0;
#pragma unroll
      for (int e = 0; e < 16; ++e) {
        int k = r0 + e;
        dst[(n << 6) + ((((k << 1) ^ ((n & 7) << 4))) >> 1)] = f2bf(src[e]);
      }
    }
  } else {
    int jc = cid - 512;
    unsigned short* dst = w1b + (size_t)jc * 4096;
    int r = tid >> 2, k0 = (tid & 3) << 4;
    const float* src = w1 + (size_t)r * 4096 + jc * 64 + k0;
#pragma unroll
    for (int e = 0; e < 16; ++e) {
      int k = k0 + e;
      dst[(r << 6) + ((((k << 1) ^ ((r & 7) << 4))) >> 1)] = f2bf(src[e]);
    }
  }
}

// ---------------------------------------------------------------------------
// P1a: convert x f32 -> xb bf16, block-contiguous [j][b][64] pre-swizzled.
// ---------------------------------------------------------------------------
__global__ __launch_bounds__(256) void convert_x_kern(const float* __restrict__ x,
                                                      unsigned short* __restrict__ xb) {
  int gid = blockIdx.x * 256 + threadIdx.x;   // 2M threads, 8 cols each
  int b = gid >> 9, c8 = gid & 511;
  int j = c8 >> 3, c0 = (c8 & 7) << 3;
  const float* src = x + (size_t)b * 4096 + j * 64 + c0;
  fx4 v0 = *(const fx4*)src;
  fx4 v1 = *(const fx4*)(src + 4);
  bfx8 o;
  o[0] = f2bf(v0[0]); o[1] = f2bf(v0[1]); o[2] = f2bf(v0[2]); o[3] = f2bf(v0[3]);
  o[4] = f2bf(v1[0]); o[5] = f2bf(v1[1]); o[6] = f2bf(v1[2]); o[7] = f2bf(v1[3]);
  size_t off = (size_t)j * 262144 + (size_t)b * 64 + ((((c0 << 1) ^ ((b & 7) << 4))) >> 1);
  *(bfx8*)(xb + off) = o;
}

// ---------------------------------------------------------------------------
// P1b: T = x @ w1^T  -> tb bf16 [4096][64] pre-swizzled (same layout as an xb block)
// 64 wgs x 256 thr; wg handles 64 rows; K-loop over 64 column blocks.
// ---------------------------------------------------------------------------
__global__ __launch_bounds__(256) void compute_t_kern(const unsigned short* __restrict__ xb,
                                                      const unsigned short* __restrict__ w1b,
                                                      unsigned short* __restrict__ tb) {
  __shared__ char smem[32768];  // A dbuf 2x8KB @0, B dbuf 2x8KB @16384
  int wg = blockIdx.x, tid = threadIdx.x, lane = tid & 63, w = tid >> 6;
  int lr = lane & 15, lkb = (lane >> 4) << 4;

  auto stage = [&](int jc, int buf) {
    const unsigned short* sa = xb + (size_t)jc * 262144 + (size_t)wg * 4096;
    const unsigned short* sb = w1b + (size_t)jc * 4096;
    char* da = smem + buf * 8192;
    char* db = smem + 16384 + buf * 8192;
#pragma unroll
    for (int i = 0; i < 2; ++i) {
      gload16(sa + tid * 8 + i * 2048, da + tid * 16 + i * 4096);
      gload16(sb + tid * 8 + i * 2048, db + tid * 16 + i * 4096);
    }
  };

  fx4 acc[4] = {};
  stage(0, 0);
#pragma unroll 1
  for (int jc = 0; jc < 64; ++jc) {
    __syncthreads();
    int cur = jc & 1;
    if (jc < 63) stage(jc + 1, cur ^ 1);
    const char* ab = smem + cur * 8192;
    const char* bb = smem + 16384 + cur * 8192;
#pragma unroll
    for (int kk = 0; kk < 2; ++kk) {
      bfx8 af = *(const bfx8*)(ab + swzb(w * 16 + lr, kk * 64 + lkb));
#pragma unroll
      for (int ni = 0; ni < 4; ++ni) {
        bfx8 bf = *(const bfx8*)(bb + swzb(ni * 16 + lr, kk * 64 + lkb));
        acc[ni] = __builtin_amdgcn_mfma_f32_16x16x32_bf16(af, bf, acc[ni], 0, 0, 0);
      }
    }
  }
#pragma unroll
  for (int ni = 0; ni < 4; ++ni)
#pragma unroll
    for (int r = 0; r < 4; ++r) {
      int row = wg * 64 + w * 16 + (lane >> 4) * 4 + r;
      int col = ni * 16 + lr;
      tb[(size_t)row * 64 + ((((col << 1) ^ ((row & 7) << 4))) >> 1)] = f2bf(acc[ni][r]);
    }
}

// ---------------------------------------------------------------------------
// P2: main butterfly GEMM. 2048 wgs = 64 p x 32 row-tiles(128). 256 thr (4 waves),
// wave computes 32 rows x 64 cols via acc[2][4] of 16x16x32 MFMA. K = 8 steps of 64.
// LDS: A dbuf 2x16KB + B dbuf 2x8KB = 48KB -> 3 wg/CU.
// ---------------------------------------------------------------------------
DEVINL void compute_step(const char* ab, const char* bb, int lr, int lkb, int w,
                         fx4 acc[2][4]) {
  bfx8 bfr[4][2];
#pragma unroll
  for (int ni = 0; ni < 4; ++ni)
#pragma unroll
    for (int kk = 0; kk < 2; ++kk)
      bfr[ni][kk] = *(const bfx8*)(bb + swzb(ni * 16 + lr, kk * 64 + lkb));
#pragma unroll
  for (int mi = 0; mi < 2; ++mi) {
    bfx8 a0 = *(const bfx8*)(ab + swzb(w * 32 + mi * 16 + lr, lkb));
    bfx8 a1 = *(const bfx8*)(ab + swzb(w * 32 + mi * 16 + lr, 64 + lkb));
#pragma unroll
    for (int ni = 0; ni < 4; ++ni) {
      acc[mi][ni] = __builtin_amdgcn_mfma_f32_16x16x32_bf16(a0, bfr[ni][0], acc[mi][ni], 0, 0, 0);
      acc[mi][ni] = __builtin_amdgcn_mfma_f32_16x16x32_bf16(a1, bfr[ni][1], acc[mi][ni], 0, 0, 0);
    }
  }
}

__global__ __launch_bounds__(256, 3) void butterfly_main(
    const unsigned short* __restrict__ xb, const unsigned short* __restrict__ tb,
    const unsigned short* __restrict__ bmat, const int* __restrict__ fwd,
    float* __restrict__ out) {
  __shared__ char smem[49152];
  int bid = blockIdx.x;
  int wid = (bid & 7) * 256 + (bid >> 3);  // bijective XCD swizzle (2048 % 8 == 0)
  int mt = wid >> 6, p = wid & 63;         // p fastest within an XCD chunk
  int tid = threadIdx.x, lane = tid & 63, w = tid >> 6;
  int lr = lane & 15, lkb = (lane >> 4) << 4;

  auto stageA = [&](int c, int buf) {
    const unsigned short* src;
    if (c < 7) {
      int j = fwd[p * 7 + c] / 7;
      src = xb + ((size_t)j * 4096 + mt * 128) * 64;
    } else {
      src = tb + (size_t)(mt * 128) * 64;
    }
    char* dst = smem + buf * 16384;
#pragma unroll
    for (int i = 0; i < 4; ++i)
      gload16(src + tid * 8 + i * 2048, dst + tid * 16 + i * 4096);
  };
  auto stageB = [&](int t, int buf) {
    const unsigned short* src = bmat + ((size_t)(p * 8 + t)) * 4096;
    char* dst = smem + 32768 + buf * 8192;
#pragma unroll
    for (int i = 0; i < 2; ++i)
      gload16(src + tid * 8 + i * 2048, dst + tid * 16 + i * 4096);
  };

  fx4 acc[2][4] = {};
  stageA(0, 0);
  stageB(0, 0);
#pragma unroll 1
  for (int t = 0; t < 8; ++t) {
    __syncthreads();  // drains vmcnt: stage(t) complete; all waves done reading prev buf
    int cur = t & 1;
    if (t < 7) { stageA(t + 1, cur ^ 1); stageB(t + 1, cur ^ 1); }
    compute_step(smem + cur * 16384, smem + 32768 + cur * 8192, lr, lkb, w, acc);
  }

  size_t rbase = (size_t)(mt * 128 + w * 32) * 4096 + p * 64;
#pragma unroll
  for (int mi = 0; mi < 2; ++mi)
#pragma unroll
    for (int ni = 0; ni < 4; ++ni)
#pragma unroll
      for (int r = 0; r < 4; ++r)
        out[rbase + (size_t)(mi * 16 + (lane >> 4) * 4 + r) * 4096 + ni * 16 + lr] =
            acc[mi][ni][r];
}

// ---------------------------------------------------------------------------
// Fallback (ws too small): naive fp32, correct but slow.
// ---------------------------------------------------------------------------
__global__ void naive_t_kern(const float* __restrict__ x, const float* __restrict__ w1,
                             float* __restrict__ t) {
  int gid = blockIdx.x * 256 + threadIdx.x;
  int b = gid >> 6, r = gid & 63;
  const float* xr = x + (size_t)b * 4096;
  const float* wr = w1 + (size_t)r * 4096;
  float s = 0.f;
  for (int k = 0; k < 4096; ++k) s += xr[k] * wr[k];
  t[gid] = s;
}

__global__ void naive_out_kern(const float* __restrict__ x, const float* __restrict__ weight,
                               const float* __restrict__ w2, const int* __restrict__ fwd,
                               const float* __restrict__ t, float* __restrict__ out) {
  size_t gid = (size_t)blockIdx.x * 256 + threadIdx.x;
  int b = (int)(gid >> 12), o = (int)(gid & 4095);
  int p = o >> 6, n = o & 63;
  float s = 0.f;
  for (int si = 0; si < 7; ++si) {
    int idx = fwd[p * 7 + si], j = idx / 7, a = idx - j * 7;
    const float* xr = x + (size_t)b * 4096 + j * 64;
    for (int k = 0; k < 64; ++k)
      s += xr[k] * weight[((size_t)(j * 64 + k) * 7 + a) * 64 + n];
  }
  const float* tr = t + (size_t)b * 64;
  const float* w2r = w2 + (size_t)o * 64;
  for (int r = 0; r < 64; ++r) s += tr[r] * w2r[r];
  out[gid] = s;
}

// ---------------------------------------------------------------------------
extern "C" void kernel_launch(void* const* d_in, const int* in_sizes, int n_in,
                              void* d_out, int out_size, void* d_ws, size_t ws_size,
                              hipStream_t stream) {
  const float* x = (const float*)d_in[0];
  const float* weight = (const float*)d_in[1];
  const float* w1 = (const float*)d_in[2];
  const float* w2 = (const float*)d_in[3];
  const int* fwd = (const int*)d_in[4];
  float* out = (float*)d_out;

  const size_t XB_E = 16777216;   // 64 blocks * 4096 * 64
  const size_t TB_E = 262144;     // 4096 * 64
  const size_t BM_E = 2097152;    // 64 * 8 * 64 * 64
  const size_t W1_E = 262144;     // 64 * 64 * 64
  const size_t WS_NEED = (XB_E + TB_E + BM_E + W1_E) * 2;  // ~37 MB

  if (ws_size >= WS_NEED) {
    unsigned short* xb = (unsigned short*)d_ws;
    unsigned short* tb = xb + XB_E;
    unsigned short* bmat = tb + TB_E;
    unsigned short* w1b = bmat + BM_E;
    prep_b_kern<<<576, 256, 0, stream>>>(weight, w1, w2, fwd, bmat, w1b);
    convert_x_kern<<<8192, 256, 0, stream>>>(x, xb);
    compute_t_kern<<<64, 256, 0, stream>>>(xb, w1b, tb);
    butterfly_main<<<2048, 256, 0, stream>>>(xb, tb, bmat, fwd, out);
  } else {
    float* t = (float*)d_ws;  // 1 MB
    naive_t_kern<<<1024, 256, 0, stream>>>(x, w1, t);
    naive_out_kern<<<65536, 256, 0, stream>>>(x, weight, w2, fwd, t, out);
  }
}

// Round 3
// 87.131 us; speedup vs baseline: 1.0855x; 1.0855x over previous
//
#include <hip/hip_runtime.h>
#include <hip/hip_bf16.h>

// Problem constants
//   x:   [4096, 4096] f32
//   w:   [4096, 7, 64] f32   (weight[j*64+k][a][n])
//   w1:  [64, 4096] f32      (lowrank_first)
//   w2:  [4096, 64] f32      (lowrank_second)
//   fwd: [64, 7] i32         (forward_indices; idx = j*7 + a)
//   out: [4096, 4096] f32
//
// out block p = sum_s x[:, j_s*64:+64] @ w[j_s,:,a_s,:]  +  T @ W2_p^T
// with T = x @ w1^T.  Per p: GEMM [4096,512] x [512,64].

#define DEVINL __device__ __forceinline__

typedef __attribute__((ext_vector_type(8))) short bfx8;   // 8 bf16 (4 VGPRs)
typedef __attribute__((ext_vector_type(4))) float fx4;

DEVINL short f2bf(float f) {   // round-to-nearest-even f32 -> bf16 bits
  unsigned u = __builtin_bit_cast(unsigned, f);
  unsigned r = 0x7FFFu + ((u >> 16) & 1u);
  return (short)((u + r) >> 16);
}

// XOR swizzle: tiles are [rows][64 cols] bf16, row stride 128 B.
// byte offset = row*128 + (colbyte ^ ((row&7)<<4))  -> ds_read_b128 conflict-free.
DEVINL int swzb(int row, int kbyte) { return (row << 7) + (kbyte ^ ((row & 7) << 4)); }

DEVINL void gload16(const void* g, void* l) {
  __builtin_amdgcn_global_load_lds(
      (const __attribute__((address_space(1))) unsigned int*)g,
      (__attribute__((address_space(3))) unsigned int*)l, 16, 0, 0);
}

// ---------------------------------------------------------------------------
// P0: build Bmat [64 p][8 t][64 n][64 k] bf16 pre-swizzled, and W1b
//     [64 jc][64 r][64 k] bf16 pre-swizzled.  (proven round-1 kernel, verbatim)
// ---------------------------------------------------------------------------
__global__ void prep_b_kern(const float* __restrict__ weight, const float* __restrict__ w1,
                            const float* __restrict__ w2, const int* __restrict__ fwd,
                            unsigned short* __restrict__ bmat, unsigned short* __restrict__ w1b) {
  int cid = blockIdx.x, tid = threadIdx.x;
  if (cid < 512) {
    int p = cid >> 3, t = cid & 7;
    unsigned short* dst = bmat + (size_t)cid * 4096;
    if (t < 7) {
      int idx = fwd[p * 7 + t];
      int j = idx / 7, a = idx - j * 7;
      int k = tid >> 2, n0 = (tid & 3) << 4;
      const float* src = weight + ((size_t)(j * 64 + k) * 7 + a) * 64 + n0;
#pragma unroll
      for (int e = 0; e < 16; ++e) {
        int n = n0 + e;
        dst[(n << 6) + ((((k << 1) ^ ((n & 7) << 4))) >> 1)] = f2bf(src[e]);
      }
    } else {
      int n = tid >> 2, r0 = (tid & 3) << 4;
      const float* src = w2 + ((size_t)(p * 64 + n)) * 64 + r0;
#pragma unroll
      for (int e = 0; e < 16; ++e) {
        int k = r0 + e;
        dst[(n << 6) + ((((k << 1) ^ ((n & 7) << 4))) >> 1)] = f2bf(src[e]);
      }
    }
  } else {
    int jc = cid - 512;
    unsigned short* dst = w1b + (size_t)jc * 4096;
    int r = tid >> 2, k0 = (tid & 3) << 4;
    const float* src = w1 + (size_t)r * 4096 + jc * 64 + k0;
#pragma unroll
    for (int e = 0; e < 16; ++e) {
      int k = k0 + e;
      dst[(r << 6) + ((((k << 1) ^ ((r & 7) << 4))) >> 1)] = f2bf(src[e]);
    }
  }
}

// ---------------------------------------------------------------------------
// P1a: convert x f32 -> xb bf16, block-contiguous [j][b][64] pre-swizzled.
//      (proven round-1 kernel, verbatim)
// ---------------------------------------------------------------------------
__global__ __launch_bounds__(256) void convert_x_kern(const float* __restrict__ x,
                                                      unsigned short* __restrict__ xb) {
  int gid = blockIdx.x * 256 + threadIdx.x;
  int b = gid >> 9, c8 = gid & 511;
  int j = c8 >> 3, c0 = (c8 & 7) << 3;
  const float* src = x + (size_t)b * 4096 + j * 64 + c0;
  fx4 v0 = *(const fx4*)src;
  fx4 v1 = *(const fx4*)(src + 4);
  bfx8 o;
  o[0] = f2bf(v0[0]); o[1] = f2bf(v0[1]); o[2] = f2bf(v0[2]); o[3] = f2bf(v0[3]);
  o[4] = f2bf(v1[0]); o[5] = f2bf(v1[1]); o[6] = f2bf(v1[2]); o[7] = f2bf(v1[3]);
  size_t off = (size_t)j * 262144 + (size_t)b * 64 + ((((c0 << 1) ^ ((b & 7) << 4))) >> 1);
  *(bfx8*)(xb + off) = o;
}

// ---------------------------------------------------------------------------
// P1b: split-K T-partials. 512 wgs = 64 row-tiles(64) x 8 K-chunks.
// Identical staging/MFMA code to the PROVEN round-1 compute_t; only the jc
// range (8 instead of 64) and the fp32 partial output differ.
// part lives in d_out (written fully before read; butterfly overwrites later).
// ---------------------------------------------------------------------------
__global__ __launch_bounds__(256) void compute_t_split(const unsigned short* __restrict__ xb,
                                                       const unsigned short* __restrict__ w1b,
                                                       float* __restrict__ part) {
  __shared__ char smem[32768];
  int rt = blockIdx.x >> 3, kc = blockIdx.x & 7;
  int tid = threadIdx.x, lane = tid & 63, w = tid >> 6;
  int lr = lane & 15, lkb = (lane >> 4) << 4;

  auto stage = [&](int jc, int buf) {
    const unsigned short* sa = xb + (size_t)(kc * 8 + jc) * 262144 + (size_t)rt * 4096;
    const unsigned short* sb = w1b + (size_t)(kc * 8 + jc) * 4096;
    char* da = smem + buf * 8192;
    char* db = smem + 16384 + buf * 8192;
#pragma unroll
    for (int i = 0; i < 2; ++i) {
      gload16(sa + tid * 8 + i * 2048, da + tid * 16 + i * 4096);
      gload16(sb + tid * 8 + i * 2048, db + tid * 16 + i * 4096);
    }
  };

  fx4 acc[4] = {};
  stage(0, 0);
#pragma unroll 1
  for (int jc = 0; jc < 8; ++jc) {
    __syncthreads();
    int cur = jc & 1;
    if (jc < 7) stage(jc + 1, cur ^ 1);
    const char* ab = smem + cur * 8192;
    const char* bb = smem + 16384 + cur * 8192;
#pragma unroll
    for (int kk = 0; kk < 2; ++kk) {
      bfx8 af = *(const bfx8*)(ab + swzb(w * 16 + lr, kk * 64 + lkb));
#pragma unroll
      for (int ni = 0; ni < 4; ++ni) {
        bfx8 bf = *(const bfx8*)(bb + swzb(ni * 16 + lr, kk * 64 + lkb));
        acc[ni] = __builtin_amdgcn_mfma_f32_16x16x32_bf16(af, bf, acc[ni], 0, 0, 0);
      }
    }
  }
  float* pb = part + (size_t)kc * 262144 + (size_t)rt * 4096;
#pragma unroll
  for (int ni = 0; ni < 4; ++ni)
#pragma unroll
    for (int r = 0; r < 4; ++r) {
      int row = w * 16 + (lane >> 4) * 4 + r;
      pb[(size_t)row * 64 + ni * 16 + lr] = acc[ni][r];
    }
}

// ---------------------------------------------------------------------------
// P1c: reduce 8 T-partials -> tb bf16 pre-swizzled. 128 wgs x 256 thr.
// Layout re-verified: logical col byte (c0*2 + d) stored at ((c0*2)^sw)+d,
// equal to (c0*2+d)^sw since d<16 and sw has bits 4..6 only.
// ---------------------------------------------------------------------------
__global__ __launch_bounds__(256) void reduce_t_kern(const float* __restrict__ part,
                                                     unsigned short* __restrict__ tb) {
  int gid = blockIdx.x * 256 + threadIdx.x;   // 32768 threads: 4096 rows x 8 col-groups
  int b = gid >> 3, c0 = (gid & 7) << 3;
  const float* pp = part + (size_t)b * 64 + c0;
  fx4 s0 = {0.f, 0.f, 0.f, 0.f}, s1 = {0.f, 0.f, 0.f, 0.f};
#pragma unroll
  for (int kc = 0; kc < 8; ++kc) {
    s0 += *(const fx4*)(pp + (size_t)kc * 262144);
    s1 += *(const fx4*)(pp + (size_t)kc * 262144 + 4);
  }
  bfx8 o;
#pragma unroll
  for (int e = 0; e < 4; ++e) { o[e] = f2bf(s0[e]); o[e + 4] = f2bf(s1[e]); }
  *(bfx8*)(tb + (size_t)b * 64 + ((((c0 << 1) ^ ((b & 7) << 4))) >> 1)) = o;
}

// ---------------------------------------------------------------------------
// P2: main butterfly GEMM. Proven round-1 256-thr/acc[2][4]/128-row kernel,
// with two changes: (1) B fragments read directly from global bmat (same swzb
// expression on the global pointer; tiles L2-hot) -> LDS 48->32 KB, 5 wg/CU;
// (2) mt-fastest XCD ordering so each p's 64KB B-set stays hot in L2.
// ---------------------------------------------------------------------------
__global__ __launch_bounds__(256, 5) void butterfly_main(
    const unsigned short* __restrict__ xb, const unsigned short* __restrict__ tb,
    const unsigned short* __restrict__ bmat, const int* __restrict__ fwd,
    float* __restrict__ out) {
  __shared__ char smem[32768];
  int bid = blockIdx.x;
  int wid = (bid & 7) * 256 + (bid >> 3);  // bijective XCD swizzle (2048 % 8 == 0)
  int p = wid >> 5, mt = wid & 31;         // mt fastest within an XCD chunk
  int tid = threadIdx.x, lane = tid & 63, w = tid >> 6;
  int lr = lane & 15, lkb = (lane >> 4) << 4;

  auto stageA = [&](int c, int buf) {
    const unsigned short* src;
    if (c < 7) {
      int j = fwd[p * 7 + c] / 7;
      src = xb + ((size_t)j * 4096 + mt * 128) * 64;
    } else {
      src = tb + (size_t)(mt * 128) * 64;
    }
    char* dst = smem + buf * 16384;
#pragma unroll
    for (int i = 0; i < 4; ++i)
      gload16(src + tid * 8 + i * 2048, dst + tid * 16 + i * 4096);
  };

  const char* bt = (const char*)(bmat + (size_t)p * 8 * 4096);  // 8 tiles x 8 KB

  fx4 acc[2][4] = {};
  stageA(0, 0);
#pragma unroll 1
  for (int t = 0; t < 8; ++t) {
    __syncthreads();  // stageA(t) complete; all waves done reading prev buf
    int cur = t & 1;
    if (t < 7) stageA(t + 1, cur ^ 1);
    const char* ab = smem + cur * 16384;
    const char* bb = bt + t * 8192;
    bfx8 bfr[4][2];
#pragma unroll
    for (int ni = 0; ni < 4; ++ni)
#pragma unroll
      for (int kk = 0; kk < 2; ++kk)
        bfr[ni][kk] = *(const bfx8*)(bb + swzb(ni * 16 + lr, kk * 64 + lkb));
#pragma unroll
    for (int mi = 0; mi < 2; ++mi) {
      bfx8 a0 = *(const bfx8*)(ab + swzb(w * 32 + mi * 16 + lr, lkb));
      bfx8 a1 = *(const bfx8*)(ab + swzb(w * 32 + mi * 16 + lr, 64 + lkb));
#pragma unroll
      for (int ni = 0; ni < 4; ++ni) {
        acc[mi][ni] = __builtin_amdgcn_mfma_f32_16x16x32_bf16(a0, bfr[ni][0], acc[mi][ni], 0, 0, 0);
        acc[mi][ni] = __builtin_amdgcn_mfma_f32_16x16x32_bf16(a1, bfr[ni][1], acc[mi][ni], 0, 0, 0);
      }
    }
  }

  size_t rbase = (size_t)(mt * 128 + w * 32) * 4096 + p * 64;
#pragma unroll
  for (int mi = 0; mi < 2; ++mi)
#pragma unroll
    for (int ni = 0; ni < 4; ++ni)
#pragma unroll
      for (int r = 0; r < 4; ++r)
        out[rbase + (size_t)(mi * 16 + (lane >> 4) * 4 + r) * 4096 + ni * 16 + lr] =
            acc[mi][ni][r];
}

// ---------------------------------------------------------------------------
// Fallback (ws tiny): naive fp32, correct but slow.
// ---------------------------------------------------------------------------
__global__ void naive_t_kern(const float* __restrict__ x, const float* __restrict__ w1,
                             float* __restrict__ t) {
  int gid = blockIdx.x * 256 + threadIdx.x;
  int b = gid >> 6, r = gid & 63;
  const float* xr = x + (size_t)b * 4096;
  const float* wr = w1 + (size_t)r * 4096;
  float s = 0.f;
  for (int k = 0; k < 4096; ++k) s += xr[k] * wr[k];
  t[gid] = s;
}

__global__ void naive_out_kern(const float* __restrict__ x, const float* __restrict__ weight,
                               const float* __restrict__ w2, const int* __restrict__ fwd,
                               const float* __restrict__ t, float* __restrict__ out) {
  size_t gid = (size_t)blockIdx.x * 256 + threadIdx.x;
  int b = (int)(gid >> 12), o = (int)(gid & 4095);
  int p = o >> 6, n = o & 63;
  float s = 0.f;
  for (int si = 0; si < 7; ++si) {
    int idx = fwd[p * 7 + si], j = idx / 7, a = idx - j * 7;
    const float* xr = x + (size_t)b * 4096 + j * 64;
    for (int k = 0; k < 64; ++k)
      s += xr[k] * weight[((size_t)(j * 64 + k) * 7 + a) * 64 + n];
  }
  const float* tr = t + (size_t)b * 64;
  const float* w2r = w2 + (size_t)o * 64;
  for (int r = 0; r < 64; ++r) s += tr[r] * w2r[r];
  out[gid] = s;
}

// ---------------------------------------------------------------------------
extern "C" void kernel_launch(void* const* d_in, const int* in_sizes, int n_in,
                              void* d_out, int out_size, void* d_ws, size_t ws_size,
                              hipStream_t stream) {
  const float* x = (const float*)d_in[0];
  const float* weight = (const float*)d_in[1];
  const float* w1 = (const float*)d_in[2];
  const float* w2 = (const float*)d_in[3];
  const int* fwd = (const int*)d_in[4];
  float* out = (float*)d_out;

  const size_t XB_E = 16777216;   // 64 * 4096 * 64
  const size_t TB_E = 262144;     // 4096 * 64
  const size_t BM_E = 2097152;    // 64 * 8 * 64 * 64
  const size_t W1_E = 262144;     // 64 * 64 * 64
  const size_t BASE_B = (XB_E + TB_E + BM_E + W1_E) * 2;  // 38797312 B (proven available)

  if (ws_size >= BASE_B) {
    unsigned short* xb = (unsigned short*)d_ws;
    unsigned short* tb = xb + XB_E;
    unsigned short* bmat = tb + TB_E;
    unsigned short* w1b = bmat + BM_E;
    float* part = out;  // 8 MB scratch inside d_out; fully overwritten by butterfly
    prep_b_kern<<<576, 256, 0, stream>>>(weight, w1, w2, fwd, bmat, w1b);
    convert_x_kern<<<8192, 256, 0, stream>>>(x, xb);
    compute_t_split<<<512, 256, 0, stream>>>(xb, w1b, part);
    reduce_t_kern<<<128, 256, 0, stream>>>(part, tb);
    butterfly_main<<<2048, 256, 0, stream>>>(xb, tb, bmat, fwd, out);
  } else {
    float* t = (float*)d_ws;
    naive_t_kern<<<1024, 256, 0, stream>>>(x, w1, t);
    naive_out_kern<<<65536, 256, 0, stream>>>(x, weight, w2, fwd, t, out);
  }
}

// Round 4
// 80.074 us; speedup vs baseline: 1.1812x; 1.0881x over previous
//
#include <hip/hip_runtime.h>
#include <hip/hip_bf16.h>

// Problem constants
//   x:   [4096, 4096] f32
//   w:   [4096, 7, 64] f32   (weight[j*64+k][a][n])
//   w1:  [64, 4096] f32      (lowrank_first)
//   w2:  [4096, 64] f32      (lowrank_second)
//   fwd: [64, 7] i32         (forward_indices; idx = j*7 + a)
//   out: [4096, 4096] f32
//
// out block p = sum_s x[:, j_s*64:+64] @ w[j_s,:,a_s,:]  +  T @ W2_p^T
// with T = x @ w1^T.  Per p: GEMM [4096,512] x [512,64].

#define DEVINL __device__ __forceinline__

typedef __attribute__((ext_vector_type(8))) short bfx8;   // 8 bf16 (4 VGPRs)
typedef __attribute__((ext_vector_type(4))) float fx4;

DEVINL short f2bf(float f) {   // round-to-nearest-even f32 -> bf16 bits
  unsigned u = __builtin_bit_cast(unsigned, f);
  unsigned r = 0x7FFFu + ((u >> 16) & 1u);
  return (short)((u + r) >> 16);
}

// XOR swizzle: tiles are [rows][64 cols] bf16, row stride 128 B.
// byte offset = row*128 + (colbyte ^ ((row&7)<<4))  -> ds_read_b128 conflict-free.
DEVINL int swzb(int row, int kbyte) { return (row << 7) + (kbyte ^ ((row & 7) << 4)); }

DEVINL void gload16(const void* g, void* l) {
  __builtin_amdgcn_global_load_lds(
      (const __attribute__((address_space(1))) unsigned int*)g,
      (__attribute__((address_space(3))) unsigned int*)l, 16, 0, 0);
}

// ---------------------------------------------------------------------------
// P0: build Bmat [64 p][8 t][64 n][64 k] bf16 pre-swizzled, and W1b
//     [64 jc][64 r][64 k] bf16 pre-swizzled.  (proven round-1 kernel, verbatim)
// ---------------------------------------------------------------------------
__global__ void prep_b_kern(const float* __restrict__ weight, const float* __restrict__ w1,
                            const float* __restrict__ w2, const int* __restrict__ fwd,
                            unsigned short* __restrict__ bmat, unsigned short* __restrict__ w1b) {
  int cid = blockIdx.x, tid = threadIdx.x;
  if (cid < 512) {
    int p = cid >> 3, t = cid & 7;
    unsigned short* dst = bmat + (size_t)cid * 4096;
    if (t < 7) {
      int idx = fwd[p * 7 + t];
      int j = idx / 7, a = idx - j * 7;
      int k = tid >> 2, n0 = (tid & 3) << 4;
      const float* src = weight + ((size_t)(j * 64 + k) * 7 + a) * 64 + n0;
#pragma unroll
      for (int e = 0; e < 16; ++e) {
        int n = n0 + e;
        dst[(n << 6) + ((((k << 1) ^ ((n & 7) << 4))) >> 1)] = f2bf(src[e]);
      }
    } else {
      int n = tid >> 2, r0 = (tid & 3) << 4;
      const float* src = w2 + ((size_t)(p * 64 + n)) * 64 + r0;
#pragma unroll
      for (int e = 0; e < 16; ++e) {
        int k = r0 + e;
        dst[(n << 6) + ((((k << 1) ^ ((n & 7) << 4))) >> 1)] = f2bf(src[e]);
      }
    }
  } else {
    int jc = cid - 512;
    unsigned short* dst = w1b + (size_t)jc * 4096;
    int r = tid >> 2, k0 = (tid & 3) << 4;
    const float* src = w1 + (size_t)r * 4096 + jc * 64 + k0;
#pragma unroll
    for (int e = 0; e < 16; ++e) {
      int k = k0 + e;
      dst[(r << 6) + ((((k << 1) ^ ((r & 7) << 4))) >> 1)] = f2bf(src[e]);
    }
  }
}

// ---------------------------------------------------------------------------
// P1a: convert x f32 -> xb bf16, block-contiguous [j][b][64] pre-swizzled.
//      (proven round-1 kernel, verbatim)
// ---------------------------------------------------------------------------
__global__ __launch_bounds__(256) void convert_x_kern(const float* __restrict__ x,
                                                      unsigned short* __restrict__ xb) {
  int gid = blockIdx.x * 256 + threadIdx.x;
  int b = gid >> 9, c8 = gid & 511;
  int j = c8 >> 3, c0 = (c8 & 7) << 3;
  const float* src = x + (size_t)b * 4096 + j * 64 + c0;
  fx4 v0 = *(const fx4*)src;
  fx4 v1 = *(const fx4*)(src + 4);
  bfx8 o;
  o[0] = f2bf(v0[0]); o[1] = f2bf(v0[1]); o[2] = f2bf(v0[2]); o[3] = f2bf(v0[3]);
  o[4] = f2bf(v1[0]); o[5] = f2bf(v1[1]); o[6] = f2bf(v1[2]); o[7] = f2bf(v1[3]);
  size_t off = (size_t)j * 262144 + (size_t)b * 64 + ((((c0 << 1) ^ ((b & 7) << 4))) >> 1);
  *(bfx8*)(xb + off) = o;
}

// ---------------------------------------------------------------------------
// P1b: split-K T-partials. 512 wgs = 64 row-tiles(64) x 8 K-chunks.
//      (proven round-3 kernel, verbatim; part lives in d_out)
// ---------------------------------------------------------------------------
__global__ __launch_bounds__(256) void compute_t_split(const unsigned short* __restrict__ xb,
                                                       const unsigned short* __restrict__ w1b,
                                                       float* __restrict__ part) {
  __shared__ char smem[32768];
  int rt = blockIdx.x >> 3, kc = blockIdx.x & 7;
  int tid = threadIdx.x, lane = tid & 63, w = tid >> 6;
  int lr = lane & 15, lkb = (lane >> 4) << 4;

  auto stage = [&](int jc, int buf) {
    const unsigned short* sa = xb + (size_t)(kc * 8 + jc) * 262144 + (size_t)rt * 4096;
    const unsigned short* sb = w1b + (size_t)(kc * 8 + jc) * 4096;
    char* da = smem + buf * 8192;
    char* db = smem + 16384 + buf * 8192;
#pragma unroll
    for (int i = 0; i < 2; ++i) {
      gload16(sa + tid * 8 + i * 2048, da + tid * 16 + i * 4096);
      gload16(sb + tid * 8 + i * 2048, db + tid * 16 + i * 4096);
    }
  };

  fx4 acc[4] = {};
  stage(0, 0);
#pragma unroll 1
  for (int jc = 0; jc < 8; ++jc) {
    __syncthreads();
    int cur = jc & 1;
    if (jc < 7) stage(jc + 1, cur ^ 1);
    const char* ab = smem + cur * 8192;
    const char* bb = smem + 16384 + cur * 8192;
#pragma unroll
    for (int kk = 0; kk < 2; ++kk) {
      bfx8 af = *(const bfx8*)(ab + swzb(w * 16 + lr, kk * 64 + lkb));
#pragma unroll
      for (int ni = 0; ni < 4; ++ni) {
        bfx8 bf = *(const bfx8*)(bb + swzb(ni * 16 + lr, kk * 64 + lkb));
        acc[ni] = __builtin_amdgcn_mfma_f32_16x16x32_bf16(af, bf, acc[ni], 0, 0, 0);
      }
    }
  }
  float* pb = part + (size_t)kc * 262144 + (size_t)rt * 4096;
#pragma unroll
  for (int ni = 0; ni < 4; ++ni)
#pragma unroll
    for (int r = 0; r < 4; ++r) {
      int row = w * 16 + (lane >> 4) * 4 + r;
      pb[(size_t)row * 64 + ni * 16 + lr] = acc[ni][r];
    }
}

// ---------------------------------------------------------------------------
// P1c: reduce 8 T-partials -> tb bf16 pre-swizzled. (proven, verbatim)
// ---------------------------------------------------------------------------
__global__ __launch_bounds__(256) void reduce_t_kern(const float* __restrict__ part,
                                                     unsigned short* __restrict__ tb) {
  int gid = blockIdx.x * 256 + threadIdx.x;   // 32768 threads: 4096 rows x 8 col-groups
  int b = gid >> 3, c0 = (gid & 7) << 3;
  const float* pp = part + (size_t)b * 64 + c0;
  fx4 s0 = {0.f, 0.f, 0.f, 0.f}, s1 = {0.f, 0.f, 0.f, 0.f};
#pragma unroll
  for (int kc = 0; kc < 8; ++kc) {
    s0 += *(const fx4*)(pp + (size_t)kc * 262144);
    s1 += *(const fx4*)(pp + (size_t)kc * 262144 + 4);
  }
  bfx8 o;
#pragma unroll
  for (int e = 0; e < 4; ++e) { o[e] = f2bf(s0[e]); o[e + 4] = f2bf(s1[e]); }
  *(bfx8*)(tb + (size_t)b * 64 + ((((c0 << 1) ^ ((b & 7) << 4))) >> 1)) = o;
}

// ---------------------------------------------------------------------------
// P2: main butterfly GEMM, 64-row tiles. 4096 wgs = 64 p x 64 row-tiles(64).
// 256 thr (4 waves), wave computes 16 rows x 64 cols via acc[4]. K = 8x64.
// B staged in LDS (round-1 proven path). LDS: A 2x8K + B 2x8K = 32 KB
// -> 5 wg/CU = 20 waves/CU. p-fastest XCD ordering (7x A-block L2 reuse).
// Compute/epilogue structurally identical to proven compute_t_split.
// ---------------------------------------------------------------------------
__global__ __launch_bounds__(256, 5) void butterfly_main(
    const unsigned short* __restrict__ xb, const unsigned short* __restrict__ tb,
    const unsigned short* __restrict__ bmat, const int* __restrict__ fwd,
    float* __restrict__ out) {
  __shared__ char smem[32768];
  int bid = blockIdx.x;
  int wid = (bid & 7) * 512 + (bid >> 3);  // bijective XCD swizzle (4096 % 8 == 0)
  int mt = wid >> 6, p = wid & 63;         // p fastest within an XCD chunk
  int tid = threadIdx.x, lane = tid & 63, w = tid >> 6;
  int lr = lane & 15, lkb = (lane >> 4) << 4;

  auto stageA = [&](int c, int buf) {
    const unsigned short* src;
    if (c < 7) {
      int j = fwd[p * 7 + c] / 7;
      src = xb + ((size_t)j * 4096 + mt * 64) * 64;
    } else {
      src = tb + (size_t)(mt * 64) * 64;
    }
    char* dst = smem + buf * 8192;
#pragma unroll
    for (int i = 0; i < 2; ++i)
      gload16(src + tid * 8 + i * 2048, dst + tid * 16 + i * 4096);
  };
  auto stageB = [&](int t, int buf) {
    const unsigned short* src = bmat + ((size_t)(p * 8 + t)) * 4096;
    char* dst = smem + 16384 + buf * 8192;
#pragma unroll
    for (int i = 0; i < 2; ++i)
      gload16(src + tid * 8 + i * 2048, dst + tid * 16 + i * 4096);
  };

  fx4 acc[4] = {};
  stageA(0, 0);
  stageB(0, 0);
#pragma unroll 1
  for (int t = 0; t < 8; ++t) {
    __syncthreads();  // stage(t) complete; all waves done reading prev buf
    int cur = t & 1;
    if (t < 7) { stageA(t + 1, cur ^ 1); stageB(t + 1, cur ^ 1); }
    const char* ab = smem + cur * 8192;
    const char* bb = smem + 16384 + cur * 8192;
#pragma unroll
    for (int kk = 0; kk < 2; ++kk) {
      bfx8 af = *(const bfx8*)(ab + swzb(w * 16 + lr, kk * 64 + lkb));
#pragma unroll
      for (int ni = 0; ni < 4; ++ni) {
        bfx8 bf = *(const bfx8*)(bb + swzb(ni * 16 + lr, kk * 64 + lkb));
        acc[ni] = __builtin_amdgcn_mfma_f32_16x16x32_bf16(af, bf, acc[ni], 0, 0, 0);
      }
    }
  }

  size_t rbase = (size_t)(mt * 64 + w * 16) * 4096 + p * 64;
#pragma unroll
  for (int ni = 0; ni < 4; ++ni)
#pragma unroll
    for (int r = 0; r < 4; ++r)
      out[rbase + (size_t)((lane >> 4) * 4 + r) * 4096 + ni * 16 + lr] = acc[ni][r];
}

// ---------------------------------------------------------------------------
// Fallback (ws tiny): naive fp32, correct but slow.
// ---------------------------------------------------------------------------
__global__ void naive_t_kern(const float* __restrict__ x, const float* __restrict__ w1,
                             float* __restrict__ t) {
  int gid = blockIdx.x * 256 + threadIdx.x;
  int b = gid >> 6, r = gid & 63;
  const float* xr = x + (size_t)b * 4096;
  const float* wr = w1 + (size_t)r * 4096;
  float s = 0.f;
  for (int k = 0; k < 4096; ++k) s += xr[k] * wr[k];
  t[gid] = s;
}

__global__ void naive_out_kern(const float* __restrict__ x, const float* __restrict__ weight,
                               const float* __restrict__ w2, const int* __restrict__ fwd,
                               const float* __restrict__ t, float* __restrict__ out) {
  size_t gid = (size_t)blockIdx.x * 256 + threadIdx.x;
  int b = (int)(gid >> 12), o = (int)(gid & 4095);
  int p = o >> 6, n = o & 63;
  float s = 0.f;
  for (int si = 0; si < 7; ++si) {
    int idx = fwd[p * 7 + si], j = idx / 7, a = idx - j * 7;
    const float* xr = x + (size_t)b * 4096 + j * 64;
    for (int k = 0; k < 64; ++k)
      s += xr[k] * weight[((size_t)(j * 64 + k) * 7 + a) * 64 + n];
  }
  const float* tr = t + (size_t)b * 64;
  const float* w2r = w2 + (size_t)o * 64;
  for (int r = 0; r < 64; ++r) s += tr[r] * w2r[r];
  out[gid] = s;
}

// ---------------------------------------------------------------------------
extern "C" void kernel_launch(void* const* d_in, const int* in_sizes, int n_in,
                              void* d_out, int out_size, void* d_ws, size_t ws_size,
                              hipStream_t stream) {
  const float* x = (const float*)d_in[0];
  const float* weight = (const float*)d_in[1];
  const float* w1 = (const float*)d_in[2];
  const float* w2 = (const float*)d_in[3];
  const int* fwd = (const int*)d_in[4];
  float* out = (float*)d_out;

  const size_t XB_E = 16777216;   // 64 * 4096 * 64
  const size_t TB_E = 262144;     // 4096 * 64
  const size_t BM_E = 2097152;    // 64 * 8 * 64 * 64
  const size_t W1_E = 262144;     // 64 * 64 * 64
  const size_t BASE_B = (XB_E + TB_E + BM_E + W1_E) * 2;  // 38797312 B (proven available)

  if (ws_size >= BASE_B) {
    unsigned short* xb = (unsigned short*)d_ws;
    unsigned short* tb = xb + XB_E;
    unsigned short* bmat = tb + TB_E;
    unsigned short* w1b = bmat + BM_E;
    float* part = out;  // 8 MB scratch inside d_out; fully overwritten by butterfly
    prep_b_kern<<<576, 256, 0, stream>>>(weight, w1, w2, fwd, bmat, w1b);
    convert_x_kern<<<8192, 256, 0, stream>>>(x, xb);
    compute_t_split<<<512, 256, 0, stream>>>(xb, w1b, part);
    reduce_t_kern<<<128, 256, 0, stream>>>(part, tb);
    butterfly_main<<<4096, 256, 0, stream>>>(xb, tb, bmat, fwd, out);
  } else {
    float* t = (float*)d_ws;
    naive_t_kern<<<1024, 256, 0, stream>>>(x, w1, t);
    naive_out_kern<<<65536, 256, 0, stream>>>(x, weight, w2, fwd, t, out);
  }
}

// Round 5
// 79.882 us; speedup vs baseline: 1.1840x; 1.0024x over previous
//
#include <hip/hip_runtime.h>
#include <hip/hip_bf16.h>

// Problem constants
//   x:   [4096, 4096] f32
//   w:   [4096, 7, 64] f32   (weight[j*64+k][a][n])
//   w1:  [64, 4096] f32      (lowrank_first)
//   w2:  [4096, 64] f32      (lowrank_second)
//   fwd: [64, 7] i32         (forward_indices; idx = j*7 + a)
//   out: [4096, 4096] f32
//
// out block p = sum_s x[:, j_s*64:+64] @ w[j_s,:,a_s,:]  +  T @ W2_p^T
// with T = x @ w1^T.  Per p: GEMM [4096,512] x [512,64].

#define DEVINL __device__ __forceinline__

typedef __attribute__((ext_vector_type(8))) short bfx8;   // 8 bf16 (4 VGPRs)
typedef __attribute__((ext_vector_type(4))) float fx4;

DEVINL short f2bf(float f) {   // round-to-nearest-even f32 -> bf16 bits
  unsigned u = __builtin_bit_cast(unsigned, f);
  unsigned r = 0x7FFFu + ((u >> 16) & 1u);
  return (short)((u + r) >> 16);
}

// XOR swizzle: tiles are [rows][64 cols] bf16, row stride 128 B.
// byte offset = row*128 + (colbyte ^ ((row&7)<<4))  -> ds_read_b128 conflict-free.
DEVINL int swzb(int row, int kbyte) { return (row << 7) + (kbyte ^ ((row & 7) << 4)); }

DEVINL void gload16(const void* g, void* l) {
  __builtin_amdgcn_global_load_lds(
      (const __attribute__((address_space(1))) unsigned int*)g,
      (__attribute__((address_space(3))) unsigned int*)l, 16, 0, 0);
}

// ---------------------------------------------------------------------------
// P0: build Bmat [64 p][8 t][64 n][64 k] bf16 pre-swizzled, and W1b
//     [64 jc][64 r][64 k] bf16 pre-swizzled.  (proven, verbatim)
// ---------------------------------------------------------------------------
__global__ void prep_b_kern(const float* __restrict__ weight, const float* __restrict__ w1,
                            const float* __restrict__ w2, const int* __restrict__ fwd,
                            unsigned short* __restrict__ bmat, unsigned short* __restrict__ w1b) {
  int cid = blockIdx.x, tid = threadIdx.x;
  if (cid < 512) {
    int p = cid >> 3, t = cid & 7;
    unsigned short* dst = bmat + (size_t)cid * 4096;
    if (t < 7) {
      int idx = fwd[p * 7 + t];
      int j = idx / 7, a = idx - j * 7;
      int k = tid >> 2, n0 = (tid & 3) << 4;
      const float* src = weight + ((size_t)(j * 64 + k) * 7 + a) * 64 + n0;
#pragma unroll
      for (int e = 0; e < 16; ++e) {
        int n = n0 + e;
        dst[(n << 6) + ((((k << 1) ^ ((n & 7) << 4))) >> 1)] = f2bf(src[e]);
      }
    } else {
      int n = tid >> 2, r0 = (tid & 3) << 4;
      const float* src = w2 + ((size_t)(p * 64 + n)) * 64 + r0;
#pragma unroll
      for (int e = 0; e < 16; ++e) {
        int k = r0 + e;
        dst[(n << 6) + ((((k << 1) ^ ((n & 7) << 4))) >> 1)] = f2bf(src[e]);
      }
    }
  } else {
    int jc = cid - 512;
    unsigned short* dst = w1b + (size_t)jc * 4096;
    int r = tid >> 2, k0 = (tid & 3) << 4;
    const float* src = w1 + (size_t)r * 4096 + jc * 64 + k0;
#pragma unroll
    for (int e = 0; e < 16; ++e) {
      int k = k0 + e;
      dst[(r << 6) + ((((k << 1) ^ ((r & 7) << 4))) >> 1)] = f2bf(src[e]);
    }
  }
}

// ---------------------------------------------------------------------------
// P1a: convert x f32 -> xb bf16, block-contiguous [j][b][64] pre-swizzled.
//      (proven, verbatim)
// ---------------------------------------------------------------------------
__global__ __launch_bounds__(256) void convert_x_kern(const float* __restrict__ x,
                                                      unsigned short* __restrict__ xb) {
  int gid = blockIdx.x * 256 + threadIdx.x;
  int b = gid >> 9, c8 = gid & 511;
  int j = c8 >> 3, c0 = (c8 & 7) << 3;
  const float* src = x + (size_t)b * 4096 + j * 64 + c0;
  fx4 v0 = *(const fx4*)src;
  fx4 v1 = *(const fx4*)(src + 4);
  bfx8 o;
  o[0] = f2bf(v0[0]); o[1] = f2bf(v0[1]); o[2] = f2bf(v0[2]); o[3] = f2bf(v0[3]);
  o[4] = f2bf(v1[0]); o[5] = f2bf(v1[1]); o[6] = f2bf(v1[2]); o[7] = f2bf(v1[3]);
  size_t off = (size_t)j * 262144 + (size_t)b * 64 + ((((c0 << 1) ^ ((b & 7) << 4))) >> 1);
  *(bfx8*)(xb + off) = o;
}

// ---------------------------------------------------------------------------
// P1b: split-K T-partials. 512 wgs = 64 row-tiles(64) x 8 K-chunks.
//      (proven, verbatim; part lives in d_out)
// ---------------------------------------------------------------------------
__global__ __launch_bounds__(256) void compute_t_split(const unsigned short* __restrict__ xb,
                                                       const unsigned short* __restrict__ w1b,
                                                       float* __restrict__ part) {
  __shared__ char smem[32768];
  int rt = blockIdx.x >> 3, kc = blockIdx.x & 7;
  int tid = threadIdx.x, lane = tid & 63, w = tid >> 6;
  int lr = lane & 15, lkb = (lane >> 4) << 4;

  auto stage = [&](int jc, int buf) {
    const unsigned short* sa = xb + (size_t)(kc * 8 + jc) * 262144 + (size_t)rt * 4096;
    const unsigned short* sb = w1b + (size_t)(kc * 8 + jc) * 4096;
    char* da = smem + buf * 8192;
    char* db = smem + 16384 + buf * 8192;
#pragma unroll
    for (int i = 0; i < 2; ++i) {
      gload16(sa + tid * 8 + i * 2048, da + tid * 16 + i * 4096);
      gload16(sb + tid * 8 + i * 2048, db + tid * 16 + i * 4096);
    }
  };

  fx4 acc[4] = {};
  stage(0, 0);
#pragma unroll 1
  for (int jc = 0; jc < 8; ++jc) {
    __syncthreads();
    int cur = jc & 1;
    if (jc < 7) stage(jc + 1, cur ^ 1);
    const char* ab = smem + cur * 8192;
    const char* bb = smem + 16384 + cur * 8192;
#pragma unroll
    for (int kk = 0; kk < 2; ++kk) {
      bfx8 af = *(const bfx8*)(ab + swzb(w * 16 + lr, kk * 64 + lkb));
#pragma unroll
      for (int ni = 0; ni < 4; ++ni) {
        bfx8 bf = *(const bfx8*)(bb + swzb(ni * 16 + lr, kk * 64 + lkb));
        acc[ni] = __builtin_amdgcn_mfma_f32_16x16x32_bf16(af, bf, acc[ni], 0, 0, 0);
      }
    }
  }
  float* pb = part + (size_t)kc * 262144 + (size_t)rt * 4096;
#pragma unroll
  for (int ni = 0; ni < 4; ++ni)
#pragma unroll
    for (int r = 0; r < 4; ++r) {
      int row = w * 16 + (lane >> 4) * 4 + r;
      pb[(size_t)row * 64 + ni * 16 + lr] = acc[ni][r];
    }
}

// ---------------------------------------------------------------------------
// P1c: reduce 8 T-partials -> tb bf16 pre-swizzled. (proven, verbatim)
// ---------------------------------------------------------------------------
__global__ __launch_bounds__(256) void reduce_t_kern(const float* __restrict__ part,
                                                     unsigned short* __restrict__ tb) {
  int gid = blockIdx.x * 256 + threadIdx.x;   // 32768 threads: 4096 rows x 8 col-groups
  int b = gid >> 3, c0 = (gid & 7) << 3;
  const float* pp = part + (size_t)b * 64 + c0;
  fx4 s0 = {0.f, 0.f, 0.f, 0.f}, s1 = {0.f, 0.f, 0.f, 0.f};
#pragma unroll
  for (int kc = 0; kc < 8; ++kc) {
    s0 += *(const fx4*)(pp + (size_t)kc * 262144);
    s1 += *(const fx4*)(pp + (size_t)kc * 262144 + 4);
  }
  bfx8 o;
#pragma unroll
  for (int e = 0; e < 4; ++e) { o[e] = f2bf(s0[e]); o[e + 4] = f2bf(s1[e]); }
  *(bfx8*)(tb + (size_t)b * 64 + ((((c0 << 1) ^ ((b & 7) << 4))) >> 1)) = o;
}

// ---------------------------------------------------------------------------
// P2: main butterfly GEMM, round-1 geometry (2048 wgs = 64 p x 32 row-tiles
// of 128; 4 waves; acc[2][4]) with a counted-vmcnt software pipeline:
//   A: 3 buffers x 16 KB (3-deep), B: 2 buffers x 8 KB (2-deep) = 64 KB LDS.
//   per iter: s_barrier; issue B(t+1), A(t+2); s_waitcnt vmcnt(10); s_barrier;
//   MFMA on A(t)/B(t).  Loads stay in flight across barriers (no vmcnt(0)
//   drain until the tail).  FIFO: entering iter t outstanding =
//   [A(t)4, B(t)2, A(t+1)4]; +B(t+1)2+A(t+2)4 = 16; vmcnt(10) retires
//   exactly A(t),B(t). Tail: t=6 -> vmcnt(6), t=7 -> vmcnt(0).
// ---------------------------------------------------------------------------
__global__ __launch_bounds__(256, 2) void butterfly_main(
    const unsigned short* __restrict__ xb, const unsigned short* __restrict__ tb,
    const unsigned short* __restrict__ bmat, const int* __restrict__ fwd,
    float* __restrict__ out) {
  __shared__ char smem[65536];  // A: 3 x 16384 @0; B: 2 x 8192 @49152
  int bid = blockIdx.x;
  int wid = (bid & 7) * 256 + (bid >> 3);  // bijective XCD swizzle (2048 % 8 == 0)
  int mt = wid >> 6, p = wid & 63;         // p fastest within an XCD chunk
  int tid = threadIdx.x, lane = tid & 63, w = tid >> 6;
  int lr = lane & 15, lkb = (lane >> 4) << 4;

  auto stageA = [&](int c, int buf) {     // 4 gload16 per thread
    const unsigned short* src;
    if (c < 7) {
      int j = fwd[p * 7 + c] / 7;
      src = xb + ((size_t)j * 4096 + mt * 128) * 64;
    } else {
      src = tb + (size_t)(mt * 128) * 64;
    }
    char* dst = smem + buf * 16384;
#pragma unroll
    for (int i = 0; i < 4; ++i)
      gload16(src + tid * 8 + i * 2048, dst + tid * 16 + i * 4096);
  };
  auto stageB = [&](int t, int buf) {     // 2 gload16 per thread
    const unsigned short* src = bmat + ((size_t)(p * 8 + t)) * 4096;
    char* dst = smem + 49152 + buf * 8192;
#pragma unroll
    for (int i = 0; i < 2; ++i)
      gload16(src + tid * 8 + i * 2048, dst + tid * 16 + i * 4096);
  };

  fx4 acc[2][4] = {};
  // Prologue issue order matters for vmcnt FIFO: A0(4), B0(2), A1(4) = 10.
  stageA(0, 0);
  stageB(0, 0);
  stageA(1, 1);

  int a3 = 0;  // t % 3
#pragma unroll 1
  for (int t = 0; t < 8; ++t) {
    __builtin_amdgcn_s_barrier();            // all waves done computing t-1
    __builtin_amdgcn_sched_barrier(0);       // nothing crosses the barrier
    if (t < 7) stageB(t + 1, (t + 1) & 1);
    if (t < 6) stageA(t + 2, a3 == 0 ? 2 : a3 - 1);  // (t+2)%3
    if (t < 6)      asm volatile("s_waitcnt vmcnt(10)" ::: "memory");
    else if (t == 6) asm volatile("s_waitcnt vmcnt(6)" ::: "memory");
    else             asm volatile("s_waitcnt vmcnt(0)" ::: "memory");
    __builtin_amdgcn_s_barrier();            // stage(t) globally complete
    __builtin_amdgcn_sched_barrier(0);       // keep ds_reads below

    const char* ab = smem + a3 * 16384;
    const char* bb = smem + 49152 + (t & 1) * 8192;
    bfx8 bfr[4][2];
#pragma unroll
    for (int ni = 0; ni < 4; ++ni)
#pragma unroll
      for (int kk = 0; kk < 2; ++kk)
        bfr[ni][kk] = *(const bfx8*)(bb + swzb(ni * 16 + lr, kk * 64 + lkb));
#pragma unroll
    for (int mi = 0; mi < 2; ++mi) {
      bfx8 a0 = *(const bfx8*)(ab + swzb(w * 32 + mi * 16 + lr, lkb));
      bfx8 a1 = *(const bfx8*)(ab + swzb(w * 32 + mi * 16 + lr, 64 + lkb));
#pragma unroll
      for (int ni = 0; ni < 4; ++ni) {
        acc[mi][ni] = __builtin_amdgcn_mfma_f32_16x16x32_bf16(a0, bfr[ni][0], acc[mi][ni], 0, 0, 0);
        acc[mi][ni] = __builtin_amdgcn_mfma_f32_16x16x32_bf16(a1, bfr[ni][1], acc[mi][ni], 0, 0, 0);
      }
    }
    a3 = (a3 == 2) ? 0 : a3 + 1;
  }

  size_t rbase = (size_t)(mt * 128 + w * 32) * 4096 + p * 64;
#pragma unroll
  for (int mi = 0; mi < 2; ++mi)
#pragma unroll
    for (int ni = 0; ni < 4; ++ni)
#pragma unroll
      for (int r = 0; r < 4; ++r)
        out[rbase + (size_t)(mi * 16 + (lane >> 4) * 4 + r) * 4096 + ni * 16 + lr] =
            acc[mi][ni][r];
}

// ---------------------------------------------------------------------------
// Fallback (ws tiny): naive fp32, correct but slow.
// ---------------------------------------------------------------------------
__global__ void naive_t_kern(const float* __restrict__ x, const float* __restrict__ w1,
                             float* __restrict__ t) {
  int gid = blockIdx.x * 256 + threadIdx.x;
  int b = gid >> 6, r = gid & 63;
  const float* xr = x + (size_t)b * 4096;
  const float* wr = w1 + (size_t)r * 4096;
  float s = 0.f;
  for (int k = 0; k < 4096; ++k) s += xr[k] * wr[k];
  t[gid] = s;
}

__global__ void naive_out_kern(const float* __restrict__ x, const float* __restrict__ weight,
                               const float* __restrict__ w2, const int* __restrict__ fwd,
                               const float* __restrict__ t, float* __restrict__ out) {
  size_t gid = (size_t)blockIdx.x * 256 + threadIdx.x;
  int b = (int)(gid >> 12), o = (int)(gid & 4095);
  int p = o >> 6, n = o & 63;
  float s = 0.f;
  for (int si = 0; si < 7; ++si) {
    int idx = fwd[p * 7 + si], j = idx / 7, a = idx - j * 7;
    const float* xr = x + (size_t)b * 4096 + j * 64;
    for (int k = 0; k < 64; ++k)
      s += xr[k] * weight[((size_t)(j * 64 + k) * 7 + a) * 64 + n];
  }
  const float* tr = t + (size_t)b * 64;
  const float* w2r = w2 + (size_t)o * 64;
  for (int r = 0; r < 64; ++r) s += tr[r] * w2r[r];
  out[gid] = s;
}

// ---------------------------------------------------------------------------
extern "C" void kernel_launch(void* const* d_in, const int* in_sizes, int n_in,
                              void* d_out, int out_size, void* d_ws, size_t ws_size,
                              hipStream_t stream) {
  const float* x = (const float*)d_in[0];
  const float* weight = (const float*)d_in[1];
  const float* w1 = (const float*)d_in[2];
  const float* w2 = (const float*)d_in[3];
  const int* fwd = (const int*)d_in[4];
  float* out = (float*)d_out;

  const size_t XB_E = 16777216;   // 64 * 4096 * 64
  const size_t TB_E = 262144;     // 4096 * 64
  const size_t BM_E = 2097152;    // 64 * 8 * 64 * 64
  const size_t W1_E = 262144;     // 64 * 64 * 64
  const size_t BASE_B = (XB_E + TB_E + BM_E + W1_E) * 2;  // 38797312 B (proven available)

  if (ws_size >= BASE_B) {
    unsigned short* xb = (unsigned short*)d_ws;
    unsigned short* tb = xb + XB_E;
    unsigned short* bmat = tb + TB_E;
    unsigned short* w1b = bmat + BM_E;
    float* part = out;  // 8 MB scratch inside d_out; fully overwritten by butterfly
    prep_b_kern<<<576, 256, 0, stream>>>(weight, w1, w2, fwd, bmat, w1b);
    convert_x_kern<<<8192, 256, 0, stream>>>(x, xb);
    compute_t_split<<<512, 256, 0, stream>>>(xb, w1b, part);
    reduce_t_kern<<<128, 256, 0, stream>>>(part, tb);
    butterfly_main<<<2048, 256, 0, stream>>>(xb, tb, bmat, fwd, out);
  } else {
    float* t = (float*)d_ws;
    naive_t_kern<<<1024, 256, 0, stream>>>(x, w1, t);
    naive_out_kern<<<65536, 256, 0, stream>>>(x, weight, w2, fwd, t, out);
  }
}

// Round 7
// 75.237 us; speedup vs baseline: 1.2571x; 1.0617x over previous
//
#include <hip/hip_runtime.h>
#include <hip/hip_bf16.h>

// Problem constants
//   x:   [4096, 4096] f32
//   w:   [4096, 7, 64] f32   (weight[j*64+k][a][n])
//   w1:  [64, 4096] f32      (lowrank_first)
//   w2:  [4096, 64] f32      (lowrank_second)
//   fwd: [64, 7] i32         (forward_indices; idx = j*7 + a)
//   out: [4096, 4096] f32
//
// out block p = sum_s x[:, j_s*64:+64] @ w[j_s,:,a_s,:]  +  T @ W2_p^T
// with T = x @ w1^T.  Per p: GEMM [4096,512] x [512,64].

#define DEVINL __device__ __forceinline__

typedef __attribute__((ext_vector_type(8))) short bfx8;   // 8 bf16 (4 VGPRs)
typedef __attribute__((ext_vector_type(4))) float fx4;

DEVINL short f2bf(float f) {   // round-to-nearest-even f32 -> bf16 bits
  unsigned u = __builtin_bit_cast(unsigned, f);
  unsigned r = 0x7FFFu + ((u >> 16) & 1u);
  return (short)((u + r) >> 16);
}

// XOR swizzle: tiles are [rows][64 cols] bf16, row stride 128 B.
// byte offset = row*128 + (colbyte ^ ((row&7)<<4))  -> ds_read_b128 conflict-free.
DEVINL int swzb(int row, int kbyte) { return (row << 7) + (kbyte ^ ((row & 7) << 4)); }

DEVINL void gload16(const void* g, void* l) {
  __builtin_amdgcn_global_load_lds(
      (const __attribute__((address_space(1))) unsigned int*)g,
      (__attribute__((address_space(3))) unsigned int*)l, 16, 0, 0);
}

// ---------------------------------------------------------------------------
// P0 (merged): blocks 0..575 = prep_b (proven verbatim); blocks 576..8767 =
// convert_x (proven verbatim, gid rebased). Independent work, one launch.
// ---------------------------------------------------------------------------
__global__ __launch_bounds__(256) void prep_all_kern(
    const float* __restrict__ weight, const float* __restrict__ w1,
    const float* __restrict__ w2, const int* __restrict__ fwd,
    const float* __restrict__ x, unsigned short* __restrict__ bmat,
    unsigned short* __restrict__ w1b, unsigned short* __restrict__ xb) {
  int cid = blockIdx.x, tid = threadIdx.x;
  if (cid >= 576) {
    // ---- convert_x (proven round-1 kernel, verbatim math) ----
    int gid = (cid - 576) * 256 + tid;
    int b = gid >> 9, c8 = gid & 511;
    int j = c8 >> 3, c0 = (c8 & 7) << 3;
    const float* src = x + (size_t)b * 4096 + j * 64 + c0;
    fx4 v0 = *(const fx4*)src;
    fx4 v1 = *(const fx4*)(src + 4);
    bfx8 o;
    o[0] = f2bf(v0[0]); o[1] = f2bf(v0[1]); o[2] = f2bf(v0[2]); o[3] = f2bf(v0[3]);
    o[4] = f2bf(v1[0]); o[5] = f2bf(v1[1]); o[6] = f2bf(v1[2]); o[7] = f2bf(v1[3]);
    size_t off = (size_t)j * 262144 + (size_t)b * 64 + ((((c0 << 1) ^ ((b & 7) << 4))) >> 1);
    *(bfx8*)(xb + off) = o;
    return;
  }
  // ---- prep_b (proven, verbatim) ----
  if (cid < 512) {
    int p = cid >> 3, t = cid & 7;
    unsigned short* dst = bmat + (size_t)cid * 4096;
    if (t < 7) {
      int idx = fwd[p * 7 + t];
      int j = idx / 7, a = idx - j * 7;
      int k = tid >> 2, n0 = (tid & 3) << 4;
      const float* src = weight + ((size_t)(j * 64 + k) * 7 + a) * 64 + n0;
#pragma unroll
      for (int e = 0; e < 16; ++e) {
        int n = n0 + e;
        dst[(n << 6) + ((((k << 1) ^ ((n & 7) << 4))) >> 1)] = f2bf(src[e]);
      }
    } else {
      int n = tid >> 2, r0 = (tid & 3) << 4;
      const float* src = w2 + ((size_t)(p * 64 + n)) * 64 + r0;
#pragma unroll
      for (int e = 0; e < 16; ++e) {
        int k = r0 + e;
        dst[(n << 6) + ((((k << 1) ^ ((n & 7) << 4))) >> 1)] = f2bf(src[e]);
      }
    }
  } else {
    int jc = cid - 512;
    unsigned short* dst = w1b + (size_t)jc * 4096;
    int r = tid >> 2, k0 = (tid & 3) << 4;
    const float* src = w1 + (size_t)r * 4096 + jc * 64 + k0;
#pragma unroll
    for (int e = 0; e < 16; ++e) {
      int k = k0 + e;
      dst[(r << 6) + ((((k << 1) ^ ((r & 7) << 4))) >> 1)] = f2bf(src[e]);
    }
  }
}

// ---------------------------------------------------------------------------
// P1b: split-K T-partials. 512 wgs = 64 row-tiles(64) x 8 K-chunks.
//      (proven, verbatim; part lives in d_out)
// ---------------------------------------------------------------------------
__global__ __launch_bounds__(256) void compute_t_split(const unsigned short* __restrict__ xb,
                                                       const unsigned short* __restrict__ w1b,
                                                       float* __restrict__ part) {
  __shared__ char smem[32768];
  int rt = blockIdx.x >> 3, kc = blockIdx.x & 7;
  int tid = threadIdx.x, lane = tid & 63, w = tid >> 6;
  int lr = lane & 15, lkb = (lane >> 4) << 4;

  auto stage = [&](int jc, int buf) {
    const unsigned short* sa = xb + (size_t)(kc * 8 + jc) * 262144 + (size_t)rt * 4096;
    const unsigned short* sb = w1b + (size_t)(kc * 8 + jc) * 4096;
    char* da = smem + buf * 8192;
    char* db = smem + 16384 + buf * 8192;
#pragma unroll
    for (int i = 0; i < 2; ++i) {
      gload16(sa + tid * 8 + i * 2048, da + tid * 16 + i * 4096);
      gload16(sb + tid * 8 + i * 2048, db + tid * 16 + i * 4096);
    }
  };

  fx4 acc[4] = {};
  stage(0, 0);
#pragma unroll 1
  for (int jc = 0; jc < 8; ++jc) {
    __syncthreads();
    int cur = jc & 1;
    if (jc < 7) stage(jc + 1, cur ^ 1);
    const char* ab = smem + cur * 8192;
    const char* bb = smem + 16384 + cur * 8192;
#pragma unroll
    for (int kk = 0; kk < 2; ++kk) {
      bfx8 af = *(const bfx8*)(ab + swzb(w * 16 + lr, kk * 64 + lkb));
#pragma unroll
      for (int ni = 0; ni < 4; ++ni) {
        bfx8 bf = *(const bfx8*)(bb + swzb(ni * 16 + lr, kk * 64 + lkb));
        acc[ni] = __builtin_amdgcn_mfma_f32_16x16x32_bf16(af, bf, acc[ni], 0, 0, 0);
      }
    }
  }
  float* pb = part + (size_t)kc * 262144 + (size_t)rt * 4096;
#pragma unroll
  for (int ni = 0; ni < 4; ++ni)
#pragma unroll
    for (int r = 0; r < 4; ++r) {
      int row = w * 16 + (lane >> 4) * 4 + r;
      pb[(size_t)row * 64 + ni * 16 + lr] = acc[ni][r];
    }
}

// ---------------------------------------------------------------------------
// P1c: reduce 8 T-partials -> tb bf16 pre-swizzled. (proven, verbatim)
// ---------------------------------------------------------------------------
__global__ __launch_bounds__(256) void reduce_t_kern(const float* __restrict__ part,
                                                     unsigned short* __restrict__ tb) {
  int gid = blockIdx.x * 256 + threadIdx.x;   // 32768 threads: 4096 rows x 8 col-groups
  int b = gid >> 3, c0 = (gid & 7) << 3;
  const float* pp = part + (size_t)b * 64 + c0;
  fx4 s0 = {0.f, 0.f, 0.f, 0.f}, s1 = {0.f, 0.f, 0.f, 0.f};
#pragma unroll
  for (int kc = 0; kc < 8; ++kc) {
    s0 += *(const fx4*)(pp + (size_t)kc * 262144);
    s1 += *(const fx4*)(pp + (size_t)kc * 262144 + 4);
  }
  bfx8 o;
#pragma unroll
  for (int e = 0; e < 4; ++e) { o[e] = f2bf(s0[e]); o[e + 4] = f2bf(s1[e]); }
  *(bfx8*)(tb + (size_t)b * 64 + ((((c0 << 1) ^ ((b & 7) << 4))) >> 1)) = o;
}

// ---------------------------------------------------------------------------
// P2: main butterfly GEMM. 2048 wgs = 64 p x 32 row-tiles(128). 512 thr
// (8 waves), wave computes 16 rows x 64 cols via acc[4]. K = 8 steps of 64.
// All staging via gload16 from pre-swizzled xb/tb/bmat (proven pattern).
// LDS: A dbuf 2x16KB + B dbuf 2x8KB = 48KB -> 3 wg/CU = 24 waves/CU.
// ---------------------------------------------------------------------------
__global__ __launch_bounds__(512, 6) void butterfly_main(
    const unsigned short* __restrict__ xb, const unsigned short* __restrict__ tb,
    const unsigned short* __restrict__ bmat, const int* __restrict__ fwd,
    float* __restrict__ out) {
  __shared__ char smem[49152];   // A dbuf 2x16K @0; B dbuf 2x8K @32768
  int bid = blockIdx.x;
  int wid = (bid & 7) * 256 + (bid >> 3);  // bijective XCD swizzle (2048 % 8 == 0)
  int mt = wid >> 6, p = wid & 63;         // p fastest within an XCD chunk
  int tid = threadIdx.x, lane = tid & 63, w = tid >> 6;
  int lr = lane & 15, lkb = (lane >> 4) << 4;

  auto stageA = [&](int c, int buf) {      // 16 KB: 512 thr x 16 B x 2
    const unsigned short* src;
    if (c < 7) {
      int j = fwd[p * 7 + c] / 7;
      src = xb + ((size_t)j * 4096 + mt * 128) * 64;
    } else {
      src = tb + (size_t)(mt * 128) * 64;
    }
    char* dst = smem + buf * 16384;
    gload16(src + tid * 8, dst + tid * 16);
    gload16(src + tid * 8 + 4096, dst + tid * 16 + 8192);
  };
  auto stageB = [&](int t, int buf) {      // 8 KB: 512 thr x 16 B
    const unsigned short* src = bmat + ((size_t)(p * 8 + t)) * 4096;
    gload16(src + tid * 8, smem + 32768 + buf * 8192 + tid * 16);
  };

  fx4 acc[4] = {};
  stageA(0, 0);
  stageB(0, 0);
#pragma unroll 1
  for (int t = 0; t < 8; ++t) {
    __syncthreads();  // stage(t) complete (vmcnt drained); prev-buf reads done
    int cur = t & 1;
    if (t < 7) { stageA(t + 1, cur ^ 1); stageB(t + 1, cur ^ 1); }
    const char* ab = smem + cur * 16384;
    const char* bb = smem + 32768 + cur * 8192;
#pragma unroll
    for (int kk = 0; kk < 2; ++kk) {
      bfx8 af = *(const bfx8*)(ab + swzb(w * 16 + lr, kk * 64 + lkb));
#pragma unroll
      for (int ni = 0; ni < 4; ++ni) {
        bfx8 bf = *(const bfx8*)(bb + swzb(ni * 16 + lr, kk * 64 + lkb));
        acc[ni] = __builtin_amdgcn_mfma_f32_16x16x32_bf16(af, bf, acc[ni], 0, 0, 0);
      }
    }
  }

  size_t rbase = (size_t)(mt * 128 + w * 16) * 4096 + p * 64;
#pragma unroll
  for (int ni = 0; ni < 4; ++ni)
#pragma unroll
    for (int r = 0; r < 4; ++r)
      out[rbase + (size_t)((lane >> 4) * 4 + r) * 4096 + ni * 16 + lr] = acc[ni][r];
}

// ---------------------------------------------------------------------------
// Fallback (ws tiny): naive fp32, correct but slow.
// ---------------------------------------------------------------------------
__global__ void naive_t_kern(const float* __restrict__ x, const float* __restrict__ w1,
                             float* __restrict__ t) {
  int gid = blockIdx.x * 256 + threadIdx.x;
  int b = gid >> 6, r = gid & 63;
  const float* xr = x + (size_t)b * 4096;
  const float* wr = w1 + (size_t)r * 4096;
  float s = 0.f;
  for (int k = 0; k < 4096; ++k) s += xr[k] * wr[k];
  t[gid] = s;
}

__global__ void naive_out_kern(const float* __restrict__ x, const float* __restrict__ weight,
                               const float* __restrict__ w2, const int* __restrict__ fwd,
                               const float* __restrict__ t, float* __restrict__ out) {
  size_t gid = (size_t)blockIdx.x * 256 + threadIdx.x;
  int b = (int)(gid >> 12), o = (int)(gid & 4095);
  int p = o >> 6, n = o & 63;
  float s = 0.f;
  for (int si = 0; si < 7; ++si) {
    int idx = fwd[p * 7 + si], j = idx / 7, a = idx - j * 7;
    const float* xr = x + (size_t)b * 4096 + j * 64;
    for (int k = 0; k < 64; ++k)
      s += xr[k] * weight[((size_t)(j * 64 + k) * 7 + a) * 64 + n];
  }
  const float* tr = t + (size_t)b * 64;
  const float* w2r = w2 + (size_t)o * 64;
  for (int r = 0; r < 64; ++r) s += tr[r] * w2r[r];
  out[gid] = s;
}

// ---------------------------------------------------------------------------
extern "C" void kernel_launch(void* const* d_in, const int* in_sizes, int n_in,
                              void* d_out, int out_size, void* d_ws, size_t ws_size,
                              hipStream_t stream) {
  const float* x = (const float*)d_in[0];
  const float* weight = (const float*)d_in[1];
  const float* w1 = (const float*)d_in[2];
  const float* w2 = (const float*)d_in[3];
  const int* fwd = (const int*)d_in[4];
  float* out = (float*)d_out;

  const size_t XB_E = 16777216;   // 64 * 4096 * 64
  const size_t TB_E = 262144;     // 4096 * 64
  const size_t BM_E = 2097152;    // 64 * 8 * 64 * 64
  const size_t W1_E = 262144;     // 64 * 64 * 64
  const size_t BASE_B = (XB_E + TB_E + BM_E + W1_E) * 2;  // 38797312 B (proven available)

  if (ws_size >= BASE_B) {
    unsigned short* xb = (unsigned short*)d_ws;
    unsigned short* tb = xb + XB_E;
    unsigned short* bmat = tb + TB_E;
    unsigned short* w1b = bmat + BM_E;
    float* part = out;  // 8 MB scratch inside d_out; fully overwritten by butterfly
    prep_all_kern<<<8768, 256, 0, stream>>>(weight, w1, w2, fwd, x, bmat, w1b, xb);
    compute_t_split<<<512, 256, 0, stream>>>(xb, w1b, part);
    reduce_t_kern<<<128, 256, 0, stream>>>(part, tb);
    butterfly_main<<<2048, 512, 0, stream>>>(xb, tb, bmat, fwd, out);
  } else {
    float* t = (float*)d_ws;
    naive_t_kern<<<1024, 256, 0, stream>>>(x, w1, t);
    naive_out_kern<<<65536, 256, 0, stream>>>(x, weight, w2, fwd, t, out);
  }
}

// Round 8
// 68.673 us; speedup vs baseline: 1.3773x; 1.0956x over previous
//
#include <hip/hip_runtime.h>
#include <hip/hip_bf16.h>

// Problem constants
//   x:   [4096, 4096] f32
//   w:   [4096, 7, 64] f32   (weight[j*64+k][a][n])
//   w1:  [64, 4096] f32      (lowrank_first)
//   w2:  [4096, 64] f32      (lowrank_second)
//   fwd: [64, 7] i32         (forward_indices; idx = j*7 + a)
//   out: [4096, 4096] f32
//
// out block p = sum_s x[:, j_s*64:+64] @ w[j_s,:,a_s,:]  +  T @ W2_p^T
// with T = x @ w1^T.  Per p: GEMM [4096,512] x [512,64].

#define DEVINL __device__ __forceinline__

typedef __attribute__((ext_vector_type(8))) short bfx8;   // 8 bf16 (4 VGPRs)
typedef __attribute__((ext_vector_type(4))) float fx4;

DEVINL short f2bf(float f) {   // round-to-nearest-even f32 -> bf16 bits
  unsigned u = __builtin_bit_cast(unsigned, f);
  unsigned r = 0x7FFFu + ((u >> 16) & 1u);
  return (short)((u + r) >> 16);
}

// XOR swizzle: tiles are [rows][64 cols] bf16, row stride 128 B.
// byte offset = row*128 + (colbyte ^ ((row&7)<<4))  -> ds_read_b128 conflict-free.
DEVINL int swzb(int row, int kbyte) { return (row << 7) + (kbyte ^ ((row & 7) << 4)); }

DEVINL void gload16(const void* g, void* l) {
  __builtin_amdgcn_global_load_lds(
      (const __attribute__((address_space(1))) unsigned int*)g,
      (__attribute__((address_space(3))) unsigned int*)l, 16, 0, 0);
}

// ---------------------------------------------------------------------------
// P0 (merged): blocks 0..575 = prep_b; blocks 576..8767 = convert_x.
// (proven round-7 kernel, verbatim)
// ---------------------------------------------------------------------------
__global__ __launch_bounds__(256) void prep_all_kern(
    const float* __restrict__ weight, const float* __restrict__ w1,
    const float* __restrict__ w2, const int* __restrict__ fwd,
    const float* __restrict__ x, unsigned short* __restrict__ bmat,
    unsigned short* __restrict__ w1b, unsigned short* __restrict__ xb) {
  int cid = blockIdx.x, tid = threadIdx.x;
  if (cid >= 576) {
    int gid = (cid - 576) * 256 + tid;
    int b = gid >> 9, c8 = gid & 511;
    int j = c8 >> 3, c0 = (c8 & 7) << 3;
    const float* src = x + (size_t)b * 4096 + j * 64 + c0;
    fx4 v0 = *(const fx4*)src;
    fx4 v1 = *(const fx4*)(src + 4);
    bfx8 o;
    o[0] = f2bf(v0[0]); o[1] = f2bf(v0[1]); o[2] = f2bf(v0[2]); o[3] = f2bf(v0[3]);
    o[4] = f2bf(v1[0]); o[5] = f2bf(v1[1]); o[6] = f2bf(v1[2]); o[7] = f2bf(v1[3]);
    size_t off = (size_t)j * 262144 + (size_t)b * 64 + ((((c0 << 1) ^ ((b & 7) << 4))) >> 1);
    *(bfx8*)(xb + off) = o;
    return;
  }
  if (cid < 512) {
    int p = cid >> 3, t = cid & 7;
    unsigned short* dst = bmat + (size_t)cid * 4096;
    if (t < 7) {
      int idx = fwd[p * 7 + t];
      int j = idx / 7, a = idx - j * 7;
      int k = tid >> 2, n0 = (tid & 3) << 4;
      const float* src = weight + ((size_t)(j * 64 + k) * 7 + a) * 64 + n0;
#pragma unroll
      for (int e = 0; e < 16; ++e) {
        int n = n0 + e;
        dst[(n << 6) + ((((k << 1) ^ ((n & 7) << 4))) >> 1)] = f2bf(src[e]);
      }
    } else {
      int n = tid >> 2, r0 = (tid & 3) << 4;
      const float* src = w2 + ((size_t)(p * 64 + n)) * 64 + r0;
#pragma unroll
      for (int e = 0; e < 16; ++e) {
        int k = r0 + e;
        dst[(n << 6) + ((((k << 1) ^ ((n & 7) << 4))) >> 1)] = f2bf(src[e]);
      }
    }
  } else {
    int jc = cid - 512;
    unsigned short* dst = w1b + (size_t)jc * 4096;
    int r = tid >> 2, k0 = (tid & 3) << 4;
    const float* src = w1 + (size_t)r * 4096 + jc * 64 + k0;
#pragma unroll
    for (int e = 0; e < 16; ++e) {
      int k = k0 + e;
      dst[(r << 6) + ((((k << 1) ^ ((r & 7) << 4))) >> 1)] = f2bf(src[e]);
    }
  }
}

// ---------------------------------------------------------------------------
// P1b: split-K T-partials. 512 wgs = 64 row-tiles(64) x 8 K-chunks.
//      (proven, verbatim; part lives in d_out)
// ---------------------------------------------------------------------------
__global__ __launch_bounds__(256) void compute_t_split(const unsigned short* __restrict__ xb,
                                                       const unsigned short* __restrict__ w1b,
                                                       float* __restrict__ part) {
  __shared__ char smem[32768];
  int rt = blockIdx.x >> 3, kc = blockIdx.x & 7;
  int tid = threadIdx.x, lane = tid & 63, w = tid >> 6;
  int lr = lane & 15, lkb = (lane >> 4) << 4;

  auto stage = [&](int jc, int buf) {
    const unsigned short* sa = xb + (size_t)(kc * 8 + jc) * 262144 + (size_t)rt * 4096;
    const unsigned short* sb = w1b + (size_t)(kc * 8 + jc) * 4096;
    char* da = smem + buf * 8192;
    char* db = smem + 16384 + buf * 8192;
#pragma unroll
    for (int i = 0; i < 2; ++i) {
      gload16(sa + tid * 8 + i * 2048, da + tid * 16 + i * 4096);
      gload16(sb + tid * 8 + i * 2048, db + tid * 16 + i * 4096);
    }
  };

  fx4 acc[4] = {};
  stage(0, 0);
#pragma unroll 1
  for (int jc = 0; jc < 8; ++jc) {
    __syncthreads();
    int cur = jc & 1;
    if (jc < 7) stage(jc + 1, cur ^ 1);
    const char* ab = smem + cur * 8192;
    const char* bb = smem + 16384 + cur * 8192;
#pragma unroll
    for (int kk = 0; kk < 2; ++kk) {
      bfx8 af = *(const bfx8*)(ab + swzb(w * 16 + lr, kk * 64 + lkb));
#pragma unroll
      for (int ni = 0; ni < 4; ++ni) {
        bfx8 bf = *(const bfx8*)(bb + swzb(ni * 16 + lr, kk * 64 + lkb));
        acc[ni] = __builtin_amdgcn_mfma_f32_16x16x32_bf16(af, bf, acc[ni], 0, 0, 0);
      }
    }
  }
  float* pb = part + (size_t)kc * 262144 + (size_t)rt * 4096;
#pragma unroll
  for (int ni = 0; ni < 4; ++ni)
#pragma unroll
    for (int r = 0; r < 4; ++r) {
      int row = w * 16 + (lane >> 4) * 4 + r;
      pb[(size_t)row * 64 + ni * 16 + lr] = acc[ni][r];
    }
}

// ---------------------------------------------------------------------------
// P1c: reduce 8 T-partials -> tb bf16 pre-swizzled. (proven, verbatim)
// ---------------------------------------------------------------------------
__global__ __launch_bounds__(256) void reduce_t_kern(const float* __restrict__ part,
                                                     unsigned short* __restrict__ tb) {
  int gid = blockIdx.x * 256 + threadIdx.x;   // 32768 threads: 4096 rows x 8 col-groups
  int b = gid >> 3, c0 = (gid & 7) << 3;
  const float* pp = part + (size_t)b * 64 + c0;
  fx4 s0 = {0.f, 0.f, 0.f, 0.f}, s1 = {0.f, 0.f, 0.f, 0.f};
#pragma unroll
  for (int kc = 0; kc < 8; ++kc) {
    s0 += *(const fx4*)(pp + (size_t)kc * 262144);
    s1 += *(const fx4*)(pp + (size_t)kc * 262144 + 4);
  }
  bfx8 o;
#pragma unroll
  for (int e = 0; e < 4; ++e) { o[e] = f2bf(s0[e]); o[e + 4] = f2bf(s1[e]); }
  *(bfx8*)(tb + (size_t)b * 64 + ((((c0 << 1) ^ ((b & 7) << 4))) >> 1)) = o;
}

// ---------------------------------------------------------------------------
// P2: multi-p butterfly GEMM. 1024 wgs = 64 mt (64-row tiles) x 16 pg
// (4 adjacent p each). 256 thr (4 waves), wave = 16 rows. Per wg, loop
// s = q*8+t over 32 stage steps (q = p sub-index, unrolled so acc[q] is
// statically indexed); staging/MFMA/dbuf discipline verbatim from the
// proven R4 64-row kernel. Epilogue writes 64 rows x 256 contiguous cols
// (1 KB strips instead of 256 B) for DRAM write locality.
// LDS: A 2x8K + B 2x8K = 32 KB. pg-fastest XCD chunking.
// ---------------------------------------------------------------------------
__global__ __launch_bounds__(256, 4) void butterfly_mp(
    const unsigned short* __restrict__ xb, const unsigned short* __restrict__ tb,
    const unsigned short* __restrict__ bmat, const int* __restrict__ fwd,
    float* __restrict__ out) {
  __shared__ char smem[32768];   // A dbuf 2x8K @0; B dbuf 2x8K @16384
  int bid = blockIdx.x;
  int wid = (bid & 7) * 128 + (bid >> 3);  // bijective XCD swizzle (1024 % 8 == 0)
  int mt = wid >> 4, pg = wid & 15;        // pg fastest within an XCD chunk
  int tid = threadIdx.x, lane = tid & 63, w = tid >> 6;
  int lr = lane & 15, lkb = (lane >> 4) << 4;

  auto stage = [&](int s, int buf) {       // s = q*8 + t
    int qq = s >> 3, tt = s & 7;
    int ps = pg * 4 + qq;
    const unsigned short* srcA;
    if (tt < 7) {
      int j = fwd[ps * 7 + tt] / 7;
      srcA = xb + ((size_t)j * 4096 + mt * 64) * 64;
    } else {
      srcA = tb + (size_t)(mt * 64) * 64;
    }
    char* da = smem + buf * 8192;
    gload16(srcA + tid * 8, da + tid * 16);
    gload16(srcA + tid * 8 + 2048, da + tid * 16 + 4096);
    const unsigned short* srcB = bmat + ((size_t)(ps * 8 + tt)) * 4096;
    char* db = smem + 16384 + buf * 8192;
    gload16(srcB + tid * 8, db + tid * 16);
    gload16(srcB + tid * 8 + 2048, db + tid * 16 + 4096);
  };

  fx4 acc[4][4] = {};
  stage(0, 0);
#pragma unroll
  for (int q = 0; q < 4; ++q) {            // unrolled -> acc[q] static
#pragma unroll 1
    for (int t = 0; t < 8; ++t) {
      int s = q * 8 + t;
      __syncthreads();                     // stage(s) complete; prev-buf reads done
      if (s < 31) stage(s + 1, (s + 1) & 1);
      const char* ab = smem + (s & 1) * 8192;
      const char* bb = smem + 16384 + (s & 1) * 8192;
#pragma unroll
      for (int kk = 0; kk < 2; ++kk) {
        bfx8 af = *(const bfx8*)(ab + swzb(w * 16 + lr, kk * 64 + lkb));
#pragma unroll
        for (int ni = 0; ni < 4; ++ni) {
          bfx8 bf = *(const bfx8*)(bb + swzb(ni * 16 + lr, kk * 64 + lkb));
          acc[q][ni] = __builtin_amdgcn_mfma_f32_16x16x32_bf16(af, bf, acc[q][ni], 0, 0, 0);
        }
      }
    }
  }

  // Epilogue: 64 rows x 256 contiguous cols (pg*256 .. pg*256+255).
  size_t rbase = (size_t)(mt * 64 + w * 16) * 4096 + pg * 256;
#pragma unroll
  for (int q = 0; q < 4; ++q)
#pragma unroll
    for (int ni = 0; ni < 4; ++ni)
#pragma unroll
      for (int r = 0; r < 4; ++r)
        out[rbase + (size_t)((lane >> 4) * 4 + r) * 4096 + q * 64 + ni * 16 + lr] =
            acc[q][ni][r];
}

// ---------------------------------------------------------------------------
// Fallback (ws tiny): naive fp32, correct but slow.
// ---------------------------------------------------------------------------
__global__ void naive_t_kern(const float* __restrict__ x, const float* __restrict__ w1,
                             float* __restrict__ t) {
  int gid = blockIdx.x * 256 + threadIdx.x;
  int b = gid >> 6, r = gid & 63;
  const float* xr = x + (size_t)b * 4096;
  const float* wr = w1 + (size_t)r * 4096;
  float s = 0.f;
  for (int k = 0; k < 4096; ++k) s += xr[k] * wr[k];
  t[gid] = s;
}

__global__ void naive_out_kern(const float* __restrict__ x, const float* __restrict__ weight,
                               const float* __restrict__ w2, const int* __restrict__ fwd,
                               const float* __restrict__ t, float* __restrict__ out) {
  size_t gid = (size_t)blockIdx.x * 256 + threadIdx.x;
  int b = (int)(gid >> 12), o = (int)(gid & 4095);
  int p = o >> 6, n = o & 63;
  float s = 0.f;
  for (int si = 0; si < 7; ++si) {
    int idx = fwd[p * 7 + si], j = idx / 7, a = idx - j * 7;
    const float* xr = x + (size_t)b * 4096 + j * 64;
    for (int k = 0; k < 64; ++k)
      s += xr[k] * weight[((size_t)(j * 64 + k) * 7 + a) * 64 + n];
  }
  const float* tr = t + (size_t)b * 64;
  const float* w2r = w2 + (size_t)o * 64;
  for (int r = 0; r < 64; ++r) s += tr[r] * w2r[r];
  out[gid] = s;
}

// ---------------------------------------------------------------------------
extern "C" void kernel_launch(void* const* d_in, const int* in_sizes, int n_in,
                              void* d_out, int out_size, void* d_ws, size_t ws_size,
                              hipStream_t stream) {
  const float* x = (const float*)d_in[0];
  const float* weight = (const float*)d_in[1];
  const float* w1 = (const float*)d_in[2];
  const float* w2 = (const float*)d_in[3];
  const int* fwd = (const int*)d_in[4];
  float* out = (float*)d_out;

  const size_t XB_E = 16777216;   // 64 * 4096 * 64
  const size_t TB_E = 262144;     // 4096 * 64
  const size_t BM_E = 2097152;    // 64 * 8 * 64 * 64
  const size_t W1_E = 262144;     // 64 * 64 * 64
  const size_t BASE_B = (XB_E + TB_E + BM_E + W1_E) * 2;  // 38797312 B (proven available)

  if (ws_size >= BASE_B) {
    unsigned short* xb = (unsigned short*)d_ws;
    unsigned short* tb = xb + XB_E;
    unsigned short* bmat = tb + TB_E;
    unsigned short* w1b = bmat + BM_E;
    float* part = out;  // 8 MB scratch inside d_out; fully overwritten by butterfly
    prep_all_kern<<<8768, 256, 0, stream>>>(weight, w1, w2, fwd, x, bmat, w1b, xb);
    compute_t_split<<<512, 256, 0, stream>>>(xb, w1b, part);
    reduce_t_kern<<<128, 256, 0, stream>>>(part, tb);
    butterfly_mp<<<1024, 256, 0, stream>>>(xb, tb, bmat, fwd, out);
  } else {
    float* t = (float*)d_ws;
    naive_t_kern<<<1024, 256, 0, stream>>>(x, w1, t);
    naive_out_kern<<<65536, 256, 0, stream>>>(x, weight, w2, fwd, t, out);
  }
}